// Round 4
// baseline (236.454 us; speedup 1.0000x reference)
//
#include <hip/hip_runtime.h>

#define T_DIM 4096
#define C_DIM 512
#define E_DIM 1024
#define KW 15
#define LN_EPS 1e-5f

#define TB 32                 // output rows per block (divides T_DIM)
#define RT (TB + KW - 1)      // rows touched per block = 46
#define NW 8                  // waves per 512-thread block

// ---------------------------------------------------------------------------
// Prep: fold gamma/beta into the taps.
//   wpad[c][j]  = gamma[c] * w[c][j]          (j = 0..14)
//   wpad[c][15] = beta[c]  * sum_j w[c][j]
// ---------------------------------------------------------------------------
__global__ __launch_bounds__(512) void fgu_prep_kernel(
    const float* __restrict__ w,
    const float* __restrict__ gamma,
    const float* __restrict__ beta,
    float* __restrict__ wpad)
{
    const int c = threadIdx.x;           // one block of 512
    const float gm = gamma[c];
    const float bt = beta[c];
    float s = 0.0f;
    float* o = wpad + c * 16;
    #pragma unroll
    for (int j = 0; j < KW; ++j) {
        const float wj = w[c * KW + j];
        s += wj;
        o[j] = gm * wj;
    }
    o[KW] = bt * s;
}

// ---------------------------------------------------------------------------
// Fused LN + 15-tap circular correlation + residual gate, NO data tile in LDS.
// Phase 1: waves compute per-row LN stats only (shuffle reduce, 8 elems/lane);
//          LDS holds just (rsigma, -mu*rsigma) per row (368 B).
// Phase 2: thread = channel; re-read the RT gate rows from global (L2-hot,
//          coalesced across the 512 threads), normalize into z[] registers,
//          then TB outputs x 15-fma dot, gate with residual, store.
// ---------------------------------------------------------------------------
__global__ __launch_bounds__(512, 4) void fgu_fused_kernel(
    const float* __restrict__ x,
    const float* __restrict__ wpad,
    float* __restrict__ out)
{
    __shared__ float2 srn[RT];           // (rsigma, -mu*rsigma) per row

    const int tid  = threadIdx.x;
    const int lane = tid & 63;
    const int wv   = tid >> 6;
    const int b    = blockIdx.x >> 7;            // T_DIM/TB = 128 tiles per b
    const int t0   = (blockIdx.x & 127) * TB;

    const float* xb = x + (size_t)b * T_DIM * E_DIM;

    // ---- Phase 1: per-row LN stats (one wave per row, 8 elems/lane)
    for (int k = wv; k < RT; k += NW) {
        const int tt = (t0 + k) & (T_DIM - 1);
        const float* gp = xb + (size_t)tt * E_DIM + C_DIM;
        const float4 a  = *(const float4*)(gp + lane * 4);
        const float4 b4 = *(const float4*)(gp + 256 + lane * 4);

        float s  = a.x + a.y + a.z + a.w + b4.x + b4.y + b4.z + b4.w;
        float ss = a.x*a.x + a.y*a.y + a.z*a.z + a.w*a.w
                 + b4.x*b4.x + b4.y*b4.y + b4.z*b4.z + b4.w*b4.w;
        #pragma unroll
        for (int off = 32; off; off >>= 1) {
            s  += __shfl_xor(s, off);
            ss += __shfl_xor(ss, off);
        }
        if (lane == 0) {
            const float mu  = s * (1.0f / (float)C_DIM);
            const float var = ss * (1.0f / (float)C_DIM) - mu * mu;
            const float rs  = rsqrtf(var + LN_EPS);
            srn[k] = make_float2(rs, -mu * rs);
        }
    }
    __syncthreads();

    // ---- Phase 2: per-channel normalize (from L2) + correlate + gate
    const int c = tid;
    const float* gc = xb + C_DIM + c;    // gate column for this channel

    float z[RT];
    #pragma unroll
    for (int k = 0; k < RT; ++k) {
        const int tt = (t0 + k) & (T_DIM - 1);
        const float2 p = srn[k];
        z[k] = fmaf(gc[(size_t)tt * E_DIM], p.x, p.y);   // (g - mu) * rsigma
    }

    // folded taps: wr[j] = gamma*w, wr[15] = beta*sum(w)
    float wr[16];
    {
        const float4* wp = (const float4*)(wpad + c * 16);
        const float4 w0 = wp[0], w1 = wp[1], w2 = wp[2], w3 = wp[3];
        wr[0]=w0.x;  wr[1]=w0.y;  wr[2]=w0.z;  wr[3]=w0.w;
        wr[4]=w1.x;  wr[5]=w1.y;  wr[6]=w1.z;  wr[7]=w1.w;
        wr[8]=w2.x;  wr[9]=w2.y;  wr[10]=w2.z; wr[11]=w2.w;
        wr[12]=w3.x; wr[13]=w3.y; wr[14]=w3.z; wr[15]=w3.w;
    }

    const float* rb = xb + (size_t)t0 * E_DIM + c;                 // residual
    float*       ob = out + ((size_t)b * T_DIM + t0) * C_DIM + c;
    #pragma unroll
    for (int i = 0; i < TB; ++i) {
        float acc = wr[KW];                 // beta * sum(w) bias term
        #pragma unroll
        for (int j = 0; j < KW; ++j)
            acc = fmaf(z[i + j], wr[j], acc);
        ob[(size_t)i * C_DIM] = rb[(size_t)i * E_DIM] * acc;
    }
}

extern "C" void kernel_launch(void* const* d_in, const int* in_sizes, int n_in,
                              void* d_out, int out_size, void* d_ws, size_t ws_size,
                              hipStream_t stream) {
    const float* x      = (const float*)d_in[0];   // [8, 4096, 1024]
    const float* weight = (const float*)d_in[1];   // [512, 15]
    const float* gamma  = (const float*)d_in[2];   // [512]
    const float* beta   = (const float*)d_in[3];   // [512]
    float* out  = (float*)d_out;                   // [8, 4096, 512]
    float* wpad = (float*)d_ws;                    // [512][16] = 32 KB

    fgu_prep_kernel<<<1, 512, 0, stream>>>(weight, gamma, beta, wpad);

    const int nblocks = 8 * (T_DIM / TB);          // 1024
    fgu_fused_kernel<<<nblocks, 512, 0, stream>>>(x, wpad, out);
}